// Round 12
// baseline (495.713 us; speedup 1.0000x reference)
//
#include <hip/hip_runtime.h>
#include <math.h>

// pGNN on MI355X. N=100000, E=1.6M, IN=256, HID=64, OUT=40. MU=0.1, P=2.5, K=2.
// Round 18: edge kernels deepened 4->8 outstanding row-gathers per wave
// (full 64-edge chunk preloaded before compute). Round-2 counters showed
// gather FETCH ~= compulsory 8-XCD table fetch -> L2-latency-bound; Little's
// law says ~13KB/CU in flight at 4-deep is marginal. 8-deep doubles MLP.
// shfl folded into load loop, gather coef shfl recomputed in compute phase
// -> VGPR ~52-58 (below 64 cliff, 8 waves/SIMD kept). Rest = round-17 best
// (k_prep W1 image, k_fat rank||mlp1, scanC-fused sh_bf, MFMA head).

#define HIDC 64
#define WPITCH 136   // 128 + 8 pad (bf16 elems); rows 272B = 16B-aligned
#define W1HALF (64 * WPITCH)     // u16 per half-array (8704)
#define W1VEC (W1HALF / 8)       // ushort8 per half-array (1088)
#define W2P 72       // 64 + 8 pad for W2^T rows

typedef unsigned short u16;
typedef short short8 __attribute__((ext_vector_type(8)));
typedef unsigned short ushort8 __attribute__((ext_vector_type(8)));
typedef float f32x4 __attribute__((ext_vector_type(4)));

__device__ inline u16 f2bf(float f) {
    union { float f; unsigned int u; } v; v.f = f;
    unsigned int u = v.u;
    u += 0x7FFFu + ((u >> 16) & 1u);     // round-to-nearest-even
    return (u16)(u >> 16);
}
__device__ inline float bf2f(u16 b) {
    union { unsigned int u; float f; } v; v.u = ((unsigned int)b) << 16;
    return v.f;
}

// ---------------- prep: W1 -> K-major padded bf16 hi/lo halves ----------------
__global__ void k_prep(const float* __restrict__ W1, u16* __restrict__ w1bf) {
    int t = blockIdx.x * 256 + threadIdx.x;   // 16384 threads
    int half = t >> 13;
    int rem = t & 8191;
    int k = rem >> 6;        // 0..127
    int n = rem & 63;        // 0..63
    float w = W1[(half * 128 + k) * HIDC + n];
    u16 hh = f2bf(w);
    u16 ll = f2bf(w - bf2f(hh));
    w1bf[half * 2 * W1HALF + n * WPITCH + k] = hh;
    w1bf[half * 2 * W1HALF + W1HALF + n * WPITCH + k] = ll;
}

// ---------------- fat: rank (atomic pass) || mlp1 (MFMA) ----------------
__global__ __launch_bounds__(256, 4)
void k_fat(const int* __restrict__ col, int* __restrict__ deg,
           int* __restrict__ rank, int E, int Brank,
           const float* __restrict__ x, const u16* __restrict__ w1bf,
           const float* __restrict__ b1, float* __restrict__ h, int N) {
    __shared__ __align__(16) u16 wsH[64 * WPITCH];   // ~17 KB (mlp1 role)
    __shared__ __align__(16) u16 wsL[64 * WPITCH];   // ~17 KB
    const int bid = blockIdx.x;
    const int Btot = gridDim.x;
    const int Bmlp = Btot - Brank;
    const int mn = (Brank < Bmlp) ? Brank : Bmlp;
    bool isRank; int rid;
    if (bid < 2 * mn) { isRank = (bid & 1) == 0; rid = bid >> 1; }
    else { isRank = (Brank > Bmlp); rid = bid - 2 * mn + mn; }

    if (isRank) {
        // ---- rank role: 1024 edges/block, 4/thread, single atomic pass ----
        int e0 = rid * 1024 + threadIdx.x * 4;
        if (e0 + 3 < E) {
            int4 c4 = *(const int4*)(col + e0);
            int4 rk;
            rk.x = atomicAdd(&deg[c4.x], 1);
            rk.y = atomicAdd(&deg[c4.y], 1);
            rk.z = atomicAdd(&deg[c4.z], 1);
            rk.w = atomicAdd(&deg[c4.w], 1);
            *(int4*)(rank + e0) = rk;
        } else {
            for (int e = e0; e < E; ++e)
                rank[e] = atomicAdd(&deg[col[e]], 1);
        }
        return;
    }

    // ---- mlp1 role: h = relu(x @ W1 + b1), 64 rows/block via MFMA ----
    const int tid = threadIdx.x;
    const int w = tid >> 6;
    const int l = tid & 63;
    const int q = l >> 4;
    const int i = l & 15;

    int aRow = rid * 64 + w * 16 + i;
    if (aRow > N - 1) aRow = N - 1;
    const float* xp = x + (size_t)aRow * 256 + q * 8;

    f32x4 acc[4];
    #pragma unroll
    for (int nt = 0; nt < 4; ++nt) acc[nt] = f32x4{0.f, 0.f, 0.f, 0.f};

    float4 c0 = *(const float4*)(xp);
    float4 c1 = *(const float4*)(xp + 4);

    // stage half 0: linear ushort8 copy (coalesced read, sequential LDS write)
    {
        const ushort8* srcH = (const ushort8*)(w1bf);
        const ushort8* srcL = (const ushort8*)(w1bf + W1HALF);
        ushort8* dstH = (ushort8*)wsH;
        ushort8* dstL = (ushort8*)wsL;
        #pragma unroll
        for (int it = 0; it < 5; ++it) {
            int idx = tid + 256 * it;
            if (idx < W1VEC) { dstH[idx] = srcH[idx]; dstL[idx] = srcL[idx]; }
        }
    }
    __syncthreads();

    #pragma unroll
    for (int kst = 0; kst < 8; ++kst) {
        if (kst == 4) {
            __syncthreads();
            const ushort8* srcH = (const ushort8*)(w1bf + 2 * W1HALF);
            const ushort8* srcL = (const ushort8*)(w1bf + 3 * W1HALF);
            ushort8* dstH = (ushort8*)wsH;
            ushort8* dstL = (ushort8*)wsL;
            #pragma unroll
            for (int it = 0; it < 5; ++it) {
                int idx = tid + 256 * it;
                if (idx < W1VEC) { dstH[idx] = srcH[idx]; dstL[idx] = srcL[idx]; }
            }
            __syncthreads();
        }
        float4 n0, n1;
        if (kst < 7) {
            n0 = *(const float4*)(xp + (kst + 1) * 32);
            n1 = *(const float4*)(xp + (kst + 1) * 32 + 4);
        }
        short8 ah, al;
        {
            float cf[8] = {c0.x, c0.y, c0.z, c0.w, c1.x, c1.y, c1.z, c1.w};
            #pragma unroll
            for (int j = 0; j < 8; ++j) {
                u16 hh = f2bf(cf[j]);
                ah[j] = (short)hh;
                al[j] = (short)f2bf(cf[j] - bf2f(hh));
            }
        }
        const int kl = (kst & 3) * 32 + q * 8;
        #pragma unroll
        for (int nt = 0; nt < 4; ++nt) {
            const int boff = (nt * 16 + i) * WPITCH + kl;
            short8 bh = *(const short8*)(&wsH[boff]);
            short8 bl = *(const short8*)(&wsL[boff]);
            acc[nt] = __builtin_amdgcn_mfma_f32_16x16x32_bf16(ah, bh, acc[nt], 0, 0, 0);
            acc[nt] = __builtin_amdgcn_mfma_f32_16x16x32_bf16(al, bh, acc[nt], 0, 0, 0);
            acc[nt] = __builtin_amdgcn_mfma_f32_16x16x32_bf16(ah, bl, acc[nt], 0, 0, 0);
        }
        c0 = n0; c1 = n1;
    }

    const int rowBaseW = rid * 64 + w * 16 + q * 4;
    float b1v[4];
    #pragma unroll
    for (int nt = 0; nt < 4; ++nt) b1v[nt] = b1[nt * 16 + i];
    #pragma unroll
    for (int r = 0; r < 4; ++r) {
        int m = rowBaseW + r;
        if (m < N) {
            #pragma unroll
            for (int nt = 0; nt < 4; ++nt) {
                int n = nt * 16 + i;
                h[(size_t)m * HIDC + n] = fmaxf(acc[nt][r] + b1v[nt], 0.0f);
            }
        }
    }
}

// ---------------- place: no atomics, unique positions ----------------
__global__ void k_place(const int* __restrict__ row, const int* __restrict__ col,
                        const int* __restrict__ off, const int* __restrict__ rank,
                        int* __restrict__ csr_src, int E) {
    int e0 = (blockIdx.x * blockDim.x + threadIdx.x) * 4;
    if (e0 + 3 < E) {
        int4 c4 = *(const int4*)(col + e0);
        int4 r4 = *(const int4*)(row + e0);
        int4 k4 = *(const int4*)(rank + e0);
        csr_src[off[c4.x] + k4.x] = r4.x;
        csr_src[off[c4.y] + k4.y] = r4.y;
        csr_src[off[c4.z] + k4.z] = r4.z;
        csr_src[off[c4.w] + k4.w] = r4.w;
    } else {
        for (int e = e0; e < E; ++e)
            csr_src[off[col[e]] + rank[e]] = row[e];
    }
}

// ---------------- block exclusive scan helper (256 threads) ----------------
__device__ inline void blockExScan256(int v, int tid, int* ex_out, int* tot_out,
                                      volatile int* wsum) {
    int lane = tid & 63, w = tid >> 6;
    int inc = v;
    #pragma unroll
    for (int d = 1; d < 64; d <<= 1) {
        int t = __shfl_up(inc, d, 64);
        if (lane >= d) inc += t;
    }
    if (lane == 63) wsum[w] = inc;
    __syncthreads();
    int wbase = 0;
    #pragma unroll
    for (int k = 0; k < 4; ++k) if (k < w) wbase += wsum[k];
    *ex_out = wbase + inc - v;
    *tot_out = wsum[0] + wsum[1] + wsum[2] + wsum[3];
    __syncthreads();
}

__global__ void k_scanA(const int* __restrict__ deg, int* __restrict__ bsum, int N) {
    __shared__ int wsum[4];
    int i = blockIdx.x * blockDim.x + threadIdx.x;
    int v = (i < N) ? deg[i] : 0;
    int ex, tot;
    blockExScan256(v, threadIdx.x, &ex, &tot, wsum);
    if (threadIdx.x == 0) bsum[blockIdx.x] = tot;
}

__global__ void k_scanB(int* __restrict__ bsum, int nb) {
    __shared__ int wsum[4];
    __shared__ int carry;
    if (threadIdx.x == 0) carry = 0;
    __syncthreads();
    for (int base = 0; base < nb; base += 256) {
        int i = base + threadIdx.x;
        int v = (i < nb) ? bsum[i] : 0;
        int ex, tot;
        blockExScan256(v, threadIdx.x, &ex, &tot, wsum);
        int c = carry;
        if (i < nb) bsum[i] = c + ex;
        __syncthreads();
        if (threadIdx.x == 0) carry = c + tot;
        __syncthreads();
    }
}

// scanC: off/dis from deg scan, then sh_bf = bf16(dis*h) for this block's rows
__global__ void k_scanC(const int* __restrict__ deg, const int* __restrict__ bsum,
                        float* __restrict__ dis, int* __restrict__ off,
                        const float* __restrict__ h, u16* __restrict__ sh_bf, int N) {
    __shared__ int wsum[4];
    __shared__ float dls[256];
    int i = blockIdx.x * blockDim.x + threadIdx.x;
    int d = (i < N) ? deg[i] : 0;
    int ex, tot;
    blockExScan256(d, threadIdx.x, &ex, &tot, wsum);
    float dv = (d > 0) ? rsqrtf((float)d) : 0.0f;
    if (i < N) {
        off[i] = bsum[blockIdx.x] + ex;
        dis[i] = dv;
    }
    dls[threadIdx.x] = dv;
    __syncthreads();
    const size_t base = (size_t)blockIdx.x * 256 * HIDC;
    #pragma unroll 4
    for (int t = 0; t < 16; ++t) {
        int vidx = threadIdx.x + 256 * t;        // float4 index in block span
        int elem = vidx * 4;
        int lrow = elem >> 6;
        if (blockIdx.x * 256 + lrow < N) {
            float4 v = *(const float4*)(h + base + elem);
            float dm = dls[lrow];
            ushort4 s;
            s.x = f2bf(v.x * dm); s.y = f2bf(v.y * dm);
            s.z = f2bf(v.z * dm); s.w = f2bf(v.w * dm);
            *(ushort4*)(sh_bf + base + elem) = s;
        }
    }
}

// ---------------- calc_M: wave/node, 8-deep pipelined chunk ----------------
// Per 64-edge chunk: issue all 8 independent ushort8 row-gathers (shfl folded
// into load loop), then compute 8 steps. Pad lanes use r=c -> diff=0 -> m=0.
__global__ void k_calcM(const int* __restrict__ csr_src, const int* __restrict__ off,
                        const int* __restrict__ deg, const float* __restrict__ dis,
                        const u16* __restrict__ scur, float* __restrict__ Mcsr,
                        float* __restrict__ alphaArr, int N) {
    int wave = (int)((blockIdx.x * (size_t)blockDim.x + threadIdx.x) >> 6);
    int lane = threadIdx.x & 63;
    if (wave >= N) return;
    const int c = wave;
    const int o = off[c];
    const int dg = deg[c];
    const int g = lane >> 3;     // edge subgroup 0..7
    const int k = lane & 7;      // dim octet 0..7
    const float dc = dis[c];
    float sc[8];
    {
        ushort8 scb = *(const ushort8*)(scur + (size_t)c * HIDC + k * 8);
        #pragma unroll
        for (int d = 0; d < 8; ++d) sc[d] = bf2f(scb[d]);
    }
    float seg = 0.0f;
    for (int base = 0; base < dg; base += 64) {
        int eI = base + lane;
        int rl = (eI < dg) ? csr_src[o + eI] : c;
        int nb = dg - base; if (nb > 64) nb = 64;
        ushort8 srb[8];
        #pragma unroll
        for (int s = 0; s < 8; ++s) {
            int r = __shfl(rl, s * 8 + g, 64);
            if (s * 8 < nb)
                srb[s] = *(const ushort8*)(scur + (size_t)r * HIDC + k * 8);
        }
        #pragma unroll
        for (int s = 0; s < 8; ++s) {
            int j = s * 8;
            if (j >= nb) break;
            float sm = 0.0f;
            #pragma unroll
            for (int d = 0; d < 8; ++d) {
                float df = bf2f(srb[s][d]) - sc[d];
                sm = fmaf(df, df, sm);
            }
            sm += __shfl_xor(sm, 1, 64);
            sm += __shfl_xor(sm, 2, 64);
            sm += __shfl_xor(sm, 4, 64);
            float m = sqrtf(sqrtf(sm));          // grad_norm^(P-2), P=2.5
            if (isinf(m)) m = 0.0f;
            seg += m;                            // pad edges give m==0
            if (k == 0 && j + g < nb) Mcsr[o + base + j + g] = m;
        }
    }
    seg += __shfl_xor(seg, 8, 64);
    seg += __shfl_xor(seg, 16, 64);
    seg += __shfl_xor(seg, 32, 64);
    if (lane == 0) alphaArr[c] = 1.0f / (dc * dc * seg + 0.08f);   // 2*MU/P
}

// ---------------- gather: 8-deep pipelined; coef shfl in compute phase ------
__global__ void k_gather(const int* __restrict__ csr_src, const int* __restrict__ off,
                         const int* __restrict__ deg, const float* __restrict__ dis,
                         const float* __restrict__ alphaArr, const float* __restrict__ Mcsr,
                         const u16* __restrict__ scur, const float* __restrict__ h,
                         float* __restrict__ outNext, u16* __restrict__ soutNext, int N) {
    int wave = (int)((blockIdx.x * (size_t)blockDim.x + threadIdx.x) >> 6);
    int lane = threadIdx.x & 63;
    if (wave >= N) return;
    const int c = wave;
    const int o = off[c];
    const int dg = deg[c];
    const int g = lane >> 3;
    const int k = lane & 7;
    const float dc = dis[c];
    float acc[8];
    #pragma unroll
    for (int d = 0; d < 8; ++d) acc[d] = 0.0f;
    for (int base = 0; base < dg; base += 64) {
        int eI = base + lane;
        bool v = eI < dg;
        int rl = v ? csr_src[o + eI] : c;
        float cl = v ? (alphaArr[rl] * Mcsr[o + eI] * dc) : 0.0f;
        int nb = dg - base; if (nb > 64) nb = 64;
        ushort8 srb[8];
        #pragma unroll
        for (int s = 0; s < 8; ++s) {
            int r = __shfl(rl, s * 8 + g, 64);
            if (s * 8 < nb)
                srb[s] = *(const ushort8*)(scur + (size_t)r * HIDC + k * 8);
        }
        #pragma unroll
        for (int s = 0; s < 8; ++s) {
            if (s * 8 >= nb) break;
            float ce = __shfl(cl, s * 8 + g, 64);
            #pragma unroll
            for (int d = 0; d < 8; ++d)
                acc[d] = fmaf(ce, bf2f(srb[s][d]), acc[d]);
        }
    }
    #pragma unroll
    for (int d = 0; d < 8; ++d) {
        acc[d] += __shfl_xor(acc[d], 8, 64);
        acc[d] += __shfl_xor(acc[d], 16, 64);
        acc[d] += __shfl_xor(acc[d], 32, 64);
    }
    if (g == 0) {
        float ba = 0.16f * alphaArr[c];          // beta = 4*MU/P * alpha
        const float4 h0 = *(const float4*)(h + (size_t)c * HIDC + k * 8);
        const float4 h1 = *(const float4*)(h + (size_t)c * HIDC + k * 8 + 4);
        float ov[8];
        ov[0] = fmaf(ba, h0.x, acc[0]); ov[1] = fmaf(ba, h0.y, acc[1]);
        ov[2] = fmaf(ba, h0.z, acc[2]); ov[3] = fmaf(ba, h0.w, acc[3]);
        ov[4] = fmaf(ba, h1.x, acc[4]); ov[5] = fmaf(ba, h1.y, acc[5]);
        ov[6] = fmaf(ba, h1.z, acc[6]); ov[7] = fmaf(ba, h1.w, acc[7]);
        if (outNext) {
            float4 o0 = make_float4(ov[0], ov[1], ov[2], ov[3]);
            float4 o1 = make_float4(ov[4], ov[5], ov[6], ov[7]);
            *(float4*)(outNext + (size_t)c * HIDC + k * 8) = o0;
            *(float4*)(outNext + (size_t)c * HIDC + k * 8 + 4) = o1;
        }
        if (soutNext) {
            ushort8 sv;
            #pragma unroll
            for (int d = 0; d < 8; ++d) sv[d] = f2bf(ov[d] * dc);
            *(ushort8*)(soutNext + (size_t)c * HIDC + k * 8) = sv;
        }
    }
}

// ---------------- head: log_softmax(out @ W2 + b2) via MFMA ----------------
__global__ __launch_bounds__(256, 4)
void k_head(const float* __restrict__ out, const float* __restrict__ W2,
            const float* __restrict__ b2, float* __restrict__ y,
            int N, int OUT) {
    __shared__ __align__(16) u16 wtH[48 * W2P];   // 6.75 KB
    __shared__ __align__(16) u16 wtL[48 * W2P];   // 6.75 KB
    const int tid = threadIdx.x;
    const int w = tid >> 6;
    const int l = tid & 63;
    const int q = l >> 4;
    const int i = l & 15;

    // stage W2^T (48 padded cols x 64 k) as bf16 hi/lo
    for (int idx = tid; idx < 48 * 64; idx += 256) {
        int n = idx >> 6, k = idx & 63;
        float v = (n < OUT) ? W2[k * OUT + n] : 0.0f;
        u16 hh = f2bf(v);
        wtH[n * W2P + k] = hh;
        wtL[n * W2P + k] = f2bf(v - bf2f(hh));
    }
    __syncthreads();

    int aRow = blockIdx.x * 64 + w * 16 + i;
    if (aRow > N - 1) aRow = N - 1;
    const float* op = out + (size_t)aRow * HIDC + q * 8;

    f32x4 acc[3];
    #pragma unroll
    for (int nt = 0; nt < 3; ++nt) acc[nt] = f32x4{0.f, 0.f, 0.f, 0.f};

    #pragma unroll
    for (int kst = 0; kst < 2; ++kst) {
        float4 c0 = *(const float4*)(op + kst * 32);
        float4 c1 = *(const float4*)(op + kst * 32 + 4);
        short8 ah, al;
        {
            float cf[8] = {c0.x, c0.y, c0.z, c0.w, c1.x, c1.y, c1.z, c1.w};
            #pragma unroll
            for (int j = 0; j < 8; ++j) {
                u16 hh = f2bf(cf[j]);
                ah[j] = (short)hh;
                al[j] = (short)f2bf(cf[j] - bf2f(hh));
            }
        }
        const int kl = kst * 32 + q * 8;
        #pragma unroll
        for (int nt = 0; nt < 3; ++nt) {
            const int boff = (nt * 16 + i) * W2P + kl;
            short8 bh = *(const short8*)(&wtH[boff]);
            short8 bl = *(const short8*)(&wtL[boff]);
            acc[nt] = __builtin_amdgcn_mfma_f32_16x16x32_bf16(ah, bh, acc[nt], 0, 0, 0);
            acc[nt] = __builtin_amdgcn_mfma_f32_16x16x32_bf16(al, bh, acc[nt], 0, 0, 0);
            acc[nt] = __builtin_amdgcn_mfma_f32_16x16x32_bf16(ah, bl, acc[nt], 0, 0, 0);
        }
    }

    float bv[3];
    #pragma unroll
    for (int nt = 0; nt < 3; ++nt) {
        int n = nt * 16 + i;
        bv[nt] = (n < OUT) ? b2[n] : 0.0f;
    }
    const int rowBaseW = blockIdx.x * 64 + w * 16 + q * 4;
    #pragma unroll
    for (int r = 0; r < 4; ++r) {
        int m = rowBaseW + r;
        float lg[3];
        #pragma unroll
        for (int nt = 0; nt < 3; ++nt) lg[nt] = acc[nt][r] + bv[nt];
        bool v2 = (32 + i) < OUT;                 // nt=2 validity (nt 0,1 always valid)
        float mx = fmaxf(lg[0], lg[1]);
        if (v2) mx = fmaxf(mx, lg[2]);
        #pragma unroll
        for (int sh = 1; sh < 16; sh <<= 1) mx = fmaxf(mx, __shfl_xor(mx, sh, 64));
        float e0 = __expf(lg[0] - mx);
        float e1 = __expf(lg[1] - mx);
        float e2 = v2 ? __expf(lg[2] - mx) : 0.0f;
        float s = e0 + e1 + e2;
        #pragma unroll
        for (int sh = 1; sh < 16; sh <<= 1) s += __shfl_xor(s, sh, 64);
        float ls = mx + __logf(s);
        if (m < N) {
            y[(size_t)m * OUT + i]      = lg[0] - ls;
            y[(size_t)m * OUT + 16 + i] = lg[1] - ls;
            if (v2) y[(size_t)m * OUT + 32 + i] = lg[2] - ls;
        }
    }
}

extern "C" void kernel_launch(void* const* d_in, const int* in_sizes, int n_in,
                              void* d_out, int out_size, void* d_ws, size_t ws_size,
                              hipStream_t stream) {
    const float* x  = (const float*)d_in[0];
    const int*   ei = (const int*)d_in[1];
    const float* W1 = (const float*)d_in[2];
    const float* b1 = (const float*)d_in[3];
    const float* W2 = (const float*)d_in[4];
    const float* b2 = (const float*)d_in[5];
    float* y = (float*)d_out;

    const int HID = in_sizes[3];            // 64
    const int IN  = in_sizes[2] / HID;      // 256
    const int OUT = in_sizes[5];            // 40
    const int N   = in_sizes[0] / IN;       // 100000
    const int E   = in_sizes[1] / 2;        // 1.6M
    const int* rowI = ei;
    const int* colI = ei + E;

    // workspace carve-up (float-granular; all counts even => 8B alignment holds)
    float* p = (float*)d_ws;
    float* dis   = p;  p += N;
    float* alpha = p;  p += N;
    float* Mcsr  = p;  p += E;
    float* h     = p;  p += (size_t)N * HID;     // raw MLP out (beta term)
    float* out2  = p;  p += (size_t)N * HID;     // final propagate output (f32)
    u16*   sh_bf = (u16*)p;  p += (size_t)N * HID / 2;   // bf16 dis*h
    u16*   sA_bf = (u16*)p;  p += (size_t)N * HID / 2;   // bf16 dis*out1
    int*   deg     = (int*)p;  p += N;
    int*   off     = (int*)p;  p += N;
    int*   csr_src = (int*)p;  p += E;
    int*   bsum    = (int*)p;  p += (N + 255) / 256;

    // rank aliases out2 (written by gather #2, long after k_place consumes it).
    // w1bf (4*8704 u16 = 68KB) aliases alpha (400KB; first written by calcM#1
    // after k_fat consumes w1bf). alpha offset = N floats -> 16B aligned.
    int* rank = (int*)out2;
    u16* w1bf = (u16*)alpha;

    const int TPB = 256;
    const int nodeBlocks = (N + TPB - 1) / TPB;
    const int nodeWaveBlocks = (N + 3) / 4;    // 4 waves/block, wave per node
    const int edge4Blocks = (E / 4 + TPB - 1) / TPB;
    const int Brank = (E + 1023) / 1024;       // rank role: 1024 edges/block
    const int Bmlp  = (N + 63) / 64;           // mlp1 role: 64 rows/block

    // prep W1 image; then fused rank || mlp1
    k_prep<<<64, TPB, 0, stream>>>(W1, w1bf);
    hipMemsetAsync(deg, 0, sizeof(int) * N, stream);
    k_fat<<<Brank + Bmlp, TPB, 0, stream>>>(colI, deg, rank, E, Brank,
                                            x, w1bf, b1, h, N);
    k_scanA<<<nodeBlocks, TPB, 0, stream>>>(deg, bsum, N);
    k_scanB<<<1, TPB, 0, stream>>>(bsum, nodeBlocks);
    k_scanC<<<nodeBlocks, TPB, 0, stream>>>(deg, bsum, dis, off, h, sh_bf, N);
    k_place<<<edge4Blocks, TPB, 0, stream>>>(rowI, colI, off, rank, csr_src, E);

    // iteration 1: scur = sh_bf -> writes only sA_bf (raw out1 never consumed)
    k_calcM<<<nodeWaveBlocks, TPB, 0, stream>>>(csr_src, off, deg, dis, sh_bf, Mcsr, alpha, N);
    k_gather<<<nodeWaveBlocks, TPB, 0, stream>>>(csr_src, off, deg, dis, alpha, Mcsr,
                                                 sh_bf, h, (float*)nullptr, sA_bf, N);

    // iteration 2: scur = sA_bf -> writes raw out2 (f32)
    k_calcM<<<nodeWaveBlocks, TPB, 0, stream>>>(csr_src, off, deg, dis, sA_bf, Mcsr, alpha, N);
    k_gather<<<nodeWaveBlocks, TPB, 0, stream>>>(csr_src, off, deg, dis, alpha, Mcsr,
                                                 sA_bf, h, out2, (u16*)nullptr, N);

    // output head via MFMA; 64 rows/block
    k_head<<<(N + 63) / 64, TPB, 0, stream>>>(out2, W2, b2, y, N, OUT);
}

// Round 13
// 468.035 us; speedup vs baseline: 1.0591x; 1.0591x over previous
//
#include <hip/hip_runtime.h>
#include <math.h>

// pGNN on MI355X. N=100000, E=1.6M, IN=256, HID=64, OUT=40. MU=0.1, P=2.5, K=2.
// Round 19: REVERT edge kernels to the 4-deep pipelined form (round-17 best,
// 469.9us). Round-18's 8-deep (srb[8] = +32 VGPR) crossed the 64-VGPR
// occupancy cliff and regressed edge dispatches ~+6.5us each (total 495.7).
// 4-deep is the MLP/occupancy sweet spot. Everything else unchanged:
// k_prep W1 image, k_fat rank||mlp1 (78us ~ atomic floor + interference),
// scanC-fused sh_bf, no-atomic place, MFMA head.

#define HIDC 64
#define WPITCH 136   // 128 + 8 pad (bf16 elems); rows 272B = 16B-aligned
#define W1HALF (64 * WPITCH)     // u16 per half-array (8704)
#define W1VEC (W1HALF / 8)       // ushort8 per half-array (1088)
#define W2P 72       // 64 + 8 pad for W2^T rows

typedef unsigned short u16;
typedef short short8 __attribute__((ext_vector_type(8)));
typedef unsigned short ushort8 __attribute__((ext_vector_type(8)));
typedef float f32x4 __attribute__((ext_vector_type(4)));

__device__ inline u16 f2bf(float f) {
    union { float f; unsigned int u; } v; v.f = f;
    unsigned int u = v.u;
    u += 0x7FFFu + ((u >> 16) & 1u);     // round-to-nearest-even
    return (u16)(u >> 16);
}
__device__ inline float bf2f(u16 b) {
    union { unsigned int u; float f; } v; v.u = ((unsigned int)b) << 16;
    return v.f;
}

// ---------------- prep: W1 -> K-major padded bf16 hi/lo halves ----------------
__global__ void k_prep(const float* __restrict__ W1, u16* __restrict__ w1bf) {
    int t = blockIdx.x * 256 + threadIdx.x;   // 16384 threads
    int half = t >> 13;
    int rem = t & 8191;
    int k = rem >> 6;        // 0..127
    int n = rem & 63;        // 0..63
    float w = W1[(half * 128 + k) * HIDC + n];
    u16 hh = f2bf(w);
    u16 ll = f2bf(w - bf2f(hh));
    w1bf[half * 2 * W1HALF + n * WPITCH + k] = hh;
    w1bf[half * 2 * W1HALF + W1HALF + n * WPITCH + k] = ll;
}

// ---------------- fat: rank (atomic pass) || mlp1 (MFMA) ----------------
__global__ __launch_bounds__(256, 4)
void k_fat(const int* __restrict__ col, int* __restrict__ deg,
           int* __restrict__ rank, int E, int Brank,
           const float* __restrict__ x, const u16* __restrict__ w1bf,
           const float* __restrict__ b1, float* __restrict__ h, int N) {
    __shared__ __align__(16) u16 wsH[64 * WPITCH];   // ~17 KB (mlp1 role)
    __shared__ __align__(16) u16 wsL[64 * WPITCH];   // ~17 KB
    const int bid = blockIdx.x;
    const int Btot = gridDim.x;
    const int Bmlp = Btot - Brank;
    const int mn = (Brank < Bmlp) ? Brank : Bmlp;
    bool isRank; int rid;
    if (bid < 2 * mn) { isRank = (bid & 1) == 0; rid = bid >> 1; }
    else { isRank = (Brank > Bmlp); rid = bid - 2 * mn + mn; }

    if (isRank) {
        // ---- rank role: 1024 edges/block, 4/thread, single atomic pass ----
        int e0 = rid * 1024 + threadIdx.x * 4;
        if (e0 + 3 < E) {
            int4 c4 = *(const int4*)(col + e0);
            int4 rk;
            rk.x = atomicAdd(&deg[c4.x], 1);
            rk.y = atomicAdd(&deg[c4.y], 1);
            rk.z = atomicAdd(&deg[c4.z], 1);
            rk.w = atomicAdd(&deg[c4.w], 1);
            *(int4*)(rank + e0) = rk;
        } else {
            for (int e = e0; e < E; ++e)
                rank[e] = atomicAdd(&deg[col[e]], 1);
        }
        return;
    }

    // ---- mlp1 role: h = relu(x @ W1 + b1), 64 rows/block via MFMA ----
    const int tid = threadIdx.x;
    const int w = tid >> 6;
    const int l = tid & 63;
    const int q = l >> 4;
    const int i = l & 15;

    int aRow = rid * 64 + w * 16 + i;
    if (aRow > N - 1) aRow = N - 1;
    const float* xp = x + (size_t)aRow * 256 + q * 8;

    f32x4 acc[4];
    #pragma unroll
    for (int nt = 0; nt < 4; ++nt) acc[nt] = f32x4{0.f, 0.f, 0.f, 0.f};

    float4 c0 = *(const float4*)(xp);
    float4 c1 = *(const float4*)(xp + 4);

    // stage half 0: linear ushort8 copy (coalesced read, sequential LDS write)
    {
        const ushort8* srcH = (const ushort8*)(w1bf);
        const ushort8* srcL = (const ushort8*)(w1bf + W1HALF);
        ushort8* dstH = (ushort8*)wsH;
        ushort8* dstL = (ushort8*)wsL;
        #pragma unroll
        for (int it = 0; it < 5; ++it) {
            int idx = tid + 256 * it;
            if (idx < W1VEC) { dstH[idx] = srcH[idx]; dstL[idx] = srcL[idx]; }
        }
    }
    __syncthreads();

    #pragma unroll
    for (int kst = 0; kst < 8; ++kst) {
        if (kst == 4) {
            __syncthreads();
            const ushort8* srcH = (const ushort8*)(w1bf + 2 * W1HALF);
            const ushort8* srcL = (const ushort8*)(w1bf + 3 * W1HALF);
            ushort8* dstH = (ushort8*)wsH;
            ushort8* dstL = (ushort8*)wsL;
            #pragma unroll
            for (int it = 0; it < 5; ++it) {
                int idx = tid + 256 * it;
                if (idx < W1VEC) { dstH[idx] = srcH[idx]; dstL[idx] = srcL[idx]; }
            }
            __syncthreads();
        }
        float4 n0, n1;
        if (kst < 7) {
            n0 = *(const float4*)(xp + (kst + 1) * 32);
            n1 = *(const float4*)(xp + (kst + 1) * 32 + 4);
        }
        short8 ah, al;
        {
            float cf[8] = {c0.x, c0.y, c0.z, c0.w, c1.x, c1.y, c1.z, c1.w};
            #pragma unroll
            for (int j = 0; j < 8; ++j) {
                u16 hh = f2bf(cf[j]);
                ah[j] = (short)hh;
                al[j] = (short)f2bf(cf[j] - bf2f(hh));
            }
        }
        const int kl = (kst & 3) * 32 + q * 8;
        #pragma unroll
        for (int nt = 0; nt < 4; ++nt) {
            const int boff = (nt * 16 + i) * WPITCH + kl;
            short8 bh = *(const short8*)(&wsH[boff]);
            short8 bl = *(const short8*)(&wsL[boff]);
            acc[nt] = __builtin_amdgcn_mfma_f32_16x16x32_bf16(ah, bh, acc[nt], 0, 0, 0);
            acc[nt] = __builtin_amdgcn_mfma_f32_16x16x32_bf16(al, bh, acc[nt], 0, 0, 0);
            acc[nt] = __builtin_amdgcn_mfma_f32_16x16x32_bf16(ah, bl, acc[nt], 0, 0, 0);
        }
        c0 = n0; c1 = n1;
    }

    const int rowBaseW = rid * 64 + w * 16 + q * 4;
    float b1v[4];
    #pragma unroll
    for (int nt = 0; nt < 4; ++nt) b1v[nt] = b1[nt * 16 + i];
    #pragma unroll
    for (int r = 0; r < 4; ++r) {
        int m = rowBaseW + r;
        if (m < N) {
            #pragma unroll
            for (int nt = 0; nt < 4; ++nt) {
                int n = nt * 16 + i;
                h[(size_t)m * HIDC + n] = fmaxf(acc[nt][r] + b1v[nt], 0.0f);
            }
        }
    }
}

// ---------------- place: no atomics, unique positions ----------------
__global__ void k_place(const int* __restrict__ row, const int* __restrict__ col,
                        const int* __restrict__ off, const int* __restrict__ rank,
                        int* __restrict__ csr_src, int E) {
    int e0 = (blockIdx.x * blockDim.x + threadIdx.x) * 4;
    if (e0 + 3 < E) {
        int4 c4 = *(const int4*)(col + e0);
        int4 r4 = *(const int4*)(row + e0);
        int4 k4 = *(const int4*)(rank + e0);
        csr_src[off[c4.x] + k4.x] = r4.x;
        csr_src[off[c4.y] + k4.y] = r4.y;
        csr_src[off[c4.z] + k4.z] = r4.z;
        csr_src[off[c4.w] + k4.w] = r4.w;
    } else {
        for (int e = e0; e < E; ++e)
            csr_src[off[col[e]] + rank[e]] = row[e];
    }
}

// ---------------- block exclusive scan helper (256 threads) ----------------
__device__ inline void blockExScan256(int v, int tid, int* ex_out, int* tot_out,
                                      volatile int* wsum) {
    int lane = tid & 63, w = tid >> 6;
    int inc = v;
    #pragma unroll
    for (int d = 1; d < 64; d <<= 1) {
        int t = __shfl_up(inc, d, 64);
        if (lane >= d) inc += t;
    }
    if (lane == 63) wsum[w] = inc;
    __syncthreads();
    int wbase = 0;
    #pragma unroll
    for (int k = 0; k < 4; ++k) if (k < w) wbase += wsum[k];
    *ex_out = wbase + inc - v;
    *tot_out = wsum[0] + wsum[1] + wsum[2] + wsum[3];
    __syncthreads();
}

__global__ void k_scanA(const int* __restrict__ deg, int* __restrict__ bsum, int N) {
    __shared__ int wsum[4];
    int i = blockIdx.x * blockDim.x + threadIdx.x;
    int v = (i < N) ? deg[i] : 0;
    int ex, tot;
    blockExScan256(v, threadIdx.x, &ex, &tot, wsum);
    if (threadIdx.x == 0) bsum[blockIdx.x] = tot;
}

__global__ void k_scanB(int* __restrict__ bsum, int nb) {
    __shared__ int wsum[4];
    __shared__ int carry;
    if (threadIdx.x == 0) carry = 0;
    __syncthreads();
    for (int base = 0; base < nb; base += 256) {
        int i = base + threadIdx.x;
        int v = (i < nb) ? bsum[i] : 0;
        int ex, tot;
        blockExScan256(v, threadIdx.x, &ex, &tot, wsum);
        int c = carry;
        if (i < nb) bsum[i] = c + ex;
        __syncthreads();
        if (threadIdx.x == 0) carry = c + tot;
        __syncthreads();
    }
}

// scanC: off/dis from deg scan, then sh_bf = bf16(dis*h) for this block's rows
__global__ void k_scanC(const int* __restrict__ deg, const int* __restrict__ bsum,
                        float* __restrict__ dis, int* __restrict__ off,
                        const float* __restrict__ h, u16* __restrict__ sh_bf, int N) {
    __shared__ int wsum[4];
    __shared__ float dls[256];
    int i = blockIdx.x * blockDim.x + threadIdx.x;
    int d = (i < N) ? deg[i] : 0;
    int ex, tot;
    blockExScan256(d, threadIdx.x, &ex, &tot, wsum);
    float dv = (d > 0) ? rsqrtf((float)d) : 0.0f;
    if (i < N) {
        off[i] = bsum[blockIdx.x] + ex;
        dis[i] = dv;
    }
    dls[threadIdx.x] = dv;
    __syncthreads();
    const size_t base = (size_t)blockIdx.x * 256 * HIDC;
    #pragma unroll 4
    for (int t = 0; t < 16; ++t) {
        int vidx = threadIdx.x + 256 * t;        // float4 index in block span
        int elem = vidx * 4;
        int lrow = elem >> 6;
        if (blockIdx.x * 256 + lrow < N) {
            float4 v = *(const float4*)(h + base + elem);
            float dm = dls[lrow];
            ushort4 s;
            s.x = f2bf(v.x * dm); s.y = f2bf(v.y * dm);
            s.z = f2bf(v.z * dm); s.w = f2bf(v.w * dm);
            *(ushort4*)(sh_bf + base + elem) = s;
        }
    }
}

// ---------------- calc_M: wave/node, 4-step pipelined batches ----------------
// Per 32-edge half-chunk: shfl 4 row indices, issue 4 independent ushort8
// gathers (4x MLP), then compute the 4 steps. Pad lanes use r=c -> m=0.
__global__ void k_calcM(const int* __restrict__ csr_src, const int* __restrict__ off,
                        const int* __restrict__ deg, const float* __restrict__ dis,
                        const u16* __restrict__ scur, float* __restrict__ Mcsr,
                        float* __restrict__ alphaArr, int N) {
    int wave = (int)((blockIdx.x * (size_t)blockDim.x + threadIdx.x) >> 6);
    int lane = threadIdx.x & 63;
    if (wave >= N) return;
    const int c = wave;
    const int o = off[c];
    const int dg = deg[c];
    const int g = lane >> 3;     // edge subgroup 0..7
    const int k = lane & 7;      // dim octet 0..7
    const float dc = dis[c];
    float sc[8];
    {
        ushort8 scb = *(const ushort8*)(scur + (size_t)c * HIDC + k * 8);
        #pragma unroll
        for (int d = 0; d < 8; ++d) sc[d] = bf2f(scb[d]);
    }
    float seg = 0.0f;
    for (int base = 0; base < dg; base += 64) {
        int eI = base + lane;
        int rl = (eI < dg) ? csr_src[o + eI] : c;
        int nb = dg - base; if (nb > 64) nb = 64;
        for (int j0 = 0; j0 < nb; j0 += 32) {
            int rr[4];
            #pragma unroll
            for (int s = 0; s < 4; ++s)
                rr[s] = __shfl(rl, j0 + s * 8 + g, 64);
            ushort8 srb[4];
            #pragma unroll
            for (int s = 0; s < 4; ++s) {
                if (j0 + s * 8 < nb)
                    srb[s] = *(const ushort8*)(scur + (size_t)rr[s] * HIDC + k * 8);
            }
            #pragma unroll
            for (int s = 0; s < 4; ++s) {
                int j = j0 + s * 8;
                if (j >= nb) break;
                float sm = 0.0f;
                #pragma unroll
                for (int d = 0; d < 8; ++d) {
                    float df = bf2f(srb[s][d]) - sc[d];
                    sm = fmaf(df, df, sm);
                }
                sm += __shfl_xor(sm, 1, 64);
                sm += __shfl_xor(sm, 2, 64);
                sm += __shfl_xor(sm, 4, 64);
                float m = sqrtf(sqrtf(sm));      // grad_norm^(P-2), P=2.5
                if (isinf(m)) m = 0.0f;
                seg += m;                        // pad edges give m==0
                if (k == 0 && j + g < nb) Mcsr[o + base + j + g] = m;
            }
        }
    }
    seg += __shfl_xor(seg, 8, 64);
    seg += __shfl_xor(seg, 16, 64);
    seg += __shfl_xor(seg, 32, 64);
    if (lane == 0) alphaArr[c] = 1.0f / (dc * dc * seg + 0.08f);   // 2*MU/P
}

// ---------------- gather: pipelined like calcM; coefs batch + shfl ----------
__global__ void k_gather(const int* __restrict__ csr_src, const int* __restrict__ off,
                         const int* __restrict__ deg, const float* __restrict__ dis,
                         const float* __restrict__ alphaArr, const float* __restrict__ Mcsr,
                         const u16* __restrict__ scur, const float* __restrict__ h,
                         float* __restrict__ outNext, u16* __restrict__ soutNext, int N) {
    int wave = (int)((blockIdx.x * (size_t)blockDim.x + threadIdx.x) >> 6);
    int lane = threadIdx.x & 63;
    if (wave >= N) return;
    const int c = wave;
    const int o = off[c];
    const int dg = deg[c];
    const int g = lane >> 3;
    const int k = lane & 7;
    const float dc = dis[c];
    float acc[8];
    #pragma unroll
    for (int d = 0; d < 8; ++d) acc[d] = 0.0f;
    for (int base = 0; base < dg; base += 64) {
        int eI = base + lane;
        bool v = eI < dg;
        int rl = v ? csr_src[o + eI] : c;
        float cl = v ? (alphaArr[rl] * Mcsr[o + eI] * dc) : 0.0f;
        int nb = dg - base; if (nb > 64) nb = 64;
        for (int j0 = 0; j0 < nb; j0 += 32) {
            int rr[4];
            float ce[4];
            #pragma unroll
            for (int s = 0; s < 4; ++s) {
                rr[s] = __shfl(rl, j0 + s * 8 + g, 64);
                ce[s] = __shfl(cl, j0 + s * 8 + g, 64);
            }
            ushort8 srb[4];
            #pragma unroll
            for (int s = 0; s < 4; ++s) {
                if (j0 + s * 8 < nb)
                    srb[s] = *(const ushort8*)(scur + (size_t)rr[s] * HIDC + k * 8);
            }
            #pragma unroll
            for (int s = 0; s < 4; ++s) {
                if (j0 + s * 8 >= nb) break;
                #pragma unroll
                for (int d = 0; d < 8; ++d)
                    acc[d] = fmaf(ce[s], bf2f(srb[s][d]), acc[d]);
            }
        }
    }
    #pragma unroll
    for (int d = 0; d < 8; ++d) {
        acc[d] += __shfl_xor(acc[d], 8, 64);
        acc[d] += __shfl_xor(acc[d], 16, 64);
        acc[d] += __shfl_xor(acc[d], 32, 64);
    }
    if (g == 0) {
        float ba = 0.16f * alphaArr[c];          // beta = 4*MU/P * alpha
        const float4 h0 = *(const float4*)(h + (size_t)c * HIDC + k * 8);
        const float4 h1 = *(const float4*)(h + (size_t)c * HIDC + k * 8 + 4);
        float ov[8];
        ov[0] = fmaf(ba, h0.x, acc[0]); ov[1] = fmaf(ba, h0.y, acc[1]);
        ov[2] = fmaf(ba, h0.z, acc[2]); ov[3] = fmaf(ba, h0.w, acc[3]);
        ov[4] = fmaf(ba, h1.x, acc[4]); ov[5] = fmaf(ba, h1.y, acc[5]);
        ov[6] = fmaf(ba, h1.z, acc[6]); ov[7] = fmaf(ba, h1.w, acc[7]);
        if (outNext) {
            float4 o0 = make_float4(ov[0], ov[1], ov[2], ov[3]);
            float4 o1 = make_float4(ov[4], ov[5], ov[6], ov[7]);
            *(float4*)(outNext + (size_t)c * HIDC + k * 8) = o0;
            *(float4*)(outNext + (size_t)c * HIDC + k * 8 + 4) = o1;
        }
        if (soutNext) {
            ushort8 sv;
            #pragma unroll
            for (int d = 0; d < 8; ++d) sv[d] = f2bf(ov[d] * dc);
            *(ushort8*)(soutNext + (size_t)c * HIDC + k * 8) = sv;
        }
    }
}

// ---------------- head: log_softmax(out @ W2 + b2) via MFMA ----------------
__global__ __launch_bounds__(256, 4)
void k_head(const float* __restrict__ out, const float* __restrict__ W2,
            const float* __restrict__ b2, float* __restrict__ y,
            int N, int OUT) {
    __shared__ __align__(16) u16 wtH[48 * W2P];   // 6.75 KB
    __shared__ __align__(16) u16 wtL[48 * W2P];   // 6.75 KB
    const int tid = threadIdx.x;
    const int w = tid >> 6;
    const int l = tid & 63;
    const int q = l >> 4;
    const int i = l & 15;

    // stage W2^T (48 padded cols x 64 k) as bf16 hi/lo
    for (int idx = tid; idx < 48 * 64; idx += 256) {
        int n = idx >> 6, k = idx & 63;
        float v = (n < OUT) ? W2[k * OUT + n] : 0.0f;
        u16 hh = f2bf(v);
        wtH[n * W2P + k] = hh;
        wtL[n * W2P + k] = f2bf(v - bf2f(hh));
    }
    __syncthreads();

    int aRow = blockIdx.x * 64 + w * 16 + i;
    if (aRow > N - 1) aRow = N - 1;
    const float* op = out + (size_t)aRow * HIDC + q * 8;

    f32x4 acc[3];
    #pragma unroll
    for (int nt = 0; nt < 3; ++nt) acc[nt] = f32x4{0.f, 0.f, 0.f, 0.f};

    #pragma unroll
    for (int kst = 0; kst < 2; ++kst) {
        float4 c0 = *(const float4*)(op + kst * 32);
        float4 c1 = *(const float4*)(op + kst * 32 + 4);
        short8 ah, al;
        {
            float cf[8] = {c0.x, c0.y, c0.z, c0.w, c1.x, c1.y, c1.z, c1.w};
            #pragma unroll
            for (int j = 0; j < 8; ++j) {
                u16 hh = f2bf(cf[j]);
                ah[j] = (short)hh;
                al[j] = (short)f2bf(cf[j] - bf2f(hh));
            }
        }
        const int kl = kst * 32 + q * 8;
        #pragma unroll
        for (int nt = 0; nt < 3; ++nt) {
            const int boff = (nt * 16 + i) * W2P + kl;
            short8 bh = *(const short8*)(&wtH[boff]);
            short8 bl = *(const short8*)(&wtL[boff]);
            acc[nt] = __builtin_amdgcn_mfma_f32_16x16x32_bf16(ah, bh, acc[nt], 0, 0, 0);
            acc[nt] = __builtin_amdgcn_mfma_f32_16x16x32_bf16(al, bh, acc[nt], 0, 0, 0);
            acc[nt] = __builtin_amdgcn_mfma_f32_16x16x32_bf16(ah, bl, acc[nt], 0, 0, 0);
        }
    }

    float bv[3];
    #pragma unroll
    for (int nt = 0; nt < 3; ++nt) {
        int n = nt * 16 + i;
        bv[nt] = (n < OUT) ? b2[n] : 0.0f;
    }
    const int rowBaseW = blockIdx.x * 64 + w * 16 + q * 4;
    #pragma unroll
    for (int r = 0; r < 4; ++r) {
        int m = rowBaseW + r;
        float lg[3];
        #pragma unroll
        for (int nt = 0; nt < 3; ++nt) lg[nt] = acc[nt][r] + bv[nt];
        bool v2 = (32 + i) < OUT;                 // nt=2 validity (nt 0,1 always valid)
        float mx = fmaxf(lg[0], lg[1]);
        if (v2) mx = fmaxf(mx, lg[2]);
        #pragma unroll
        for (int sh = 1; sh < 16; sh <<= 1) mx = fmaxf(mx, __shfl_xor(mx, sh, 64));
        float e0 = __expf(lg[0] - mx);
        float e1 = __expf(lg[1] - mx);
        float e2 = v2 ? __expf(lg[2] - mx) : 0.0f;
        float s = e0 + e1 + e2;
        #pragma unroll
        for (int sh = 1; sh < 16; sh <<= 1) s += __shfl_xor(s, sh, 64);
        float ls = mx + __logf(s);
        if (m < N) {
            y[(size_t)m * OUT + i]      = lg[0] - ls;
            y[(size_t)m * OUT + 16 + i] = lg[1] - ls;
            if (v2) y[(size_t)m * OUT + 32 + i] = lg[2] - ls;
        }
    }
}

extern "C" void kernel_launch(void* const* d_in, const int* in_sizes, int n_in,
                              void* d_out, int out_size, void* d_ws, size_t ws_size,
                              hipStream_t stream) {
    const float* x  = (const float*)d_in[0];
    const int*   ei = (const int*)d_in[1];
    const float* W1 = (const float*)d_in[2];
    const float* b1 = (const float*)d_in[3];
    const float* W2 = (const float*)d_in[4];
    const float* b2 = (const float*)d_in[5];
    float* y = (float*)d_out;

    const int HID = in_sizes[3];            // 64
    const int IN  = in_sizes[2] / HID;      // 256
    const int OUT = in_sizes[5];            // 40
    const int N   = in_sizes[0] / IN;       // 100000
    const int E   = in_sizes[1] / 2;        // 1.6M
    const int* rowI = ei;
    const int* colI = ei + E;

    // workspace carve-up (float-granular; all counts even => 8B alignment holds)
    float* p = (float*)d_ws;
    float* dis   = p;  p += N;
    float* alpha = p;  p += N;
    float* Mcsr  = p;  p += E;
    float* h     = p;  p += (size_t)N * HID;     // raw MLP out (beta term)
    float* out2  = p;  p += (size_t)N * HID;     // final propagate output (f32)
    u16*   sh_bf = (u16*)p;  p += (size_t)N * HID / 2;   // bf16 dis*h
    u16*   sA_bf = (u16*)p;  p += (size_t)N * HID / 2;   // bf16 dis*out1
    int*   deg     = (int*)p;  p += N;
    int*   off     = (int*)p;  p += N;
    int*   csr_src = (int*)p;  p += E;
    int*   bsum    = (int*)p;  p += (N + 255) / 256;

    // rank aliases out2 (written by gather #2, long after k_place consumes it).
    // w1bf (4*8704 u16 = 68KB) aliases alpha (400KB; first written by calcM#1
    // after k_fat consumes w1bf). alpha offset = N floats -> 16B aligned.
    int* rank = (int*)out2;
    u16* w1bf = (u16*)alpha;

    const int TPB = 256;
    const int nodeBlocks = (N + TPB - 1) / TPB;
    const int nodeWaveBlocks = (N + 3) / 4;    // 4 waves/block, wave per node
    const int edge4Blocks = (E / 4 + TPB - 1) / TPB;
    const int Brank = (E + 1023) / 1024;       // rank role: 1024 edges/block
    const int Bmlp  = (N + 63) / 64;           // mlp1 role: 64 rows/block

    // prep W1 image; then fused rank || mlp1
    k_prep<<<64, TPB, 0, stream>>>(W1, w1bf);
    hipMemsetAsync(deg, 0, sizeof(int) * N, stream);
    k_fat<<<Brank + Bmlp, TPB, 0, stream>>>(colI, deg, rank, E, Brank,
                                            x, w1bf, b1, h, N);
    k_scanA<<<nodeBlocks, TPB, 0, stream>>>(deg, bsum, N);
    k_scanB<<<1, TPB, 0, stream>>>(bsum, nodeBlocks);
    k_scanC<<<nodeBlocks, TPB, 0, stream>>>(deg, bsum, dis, off, h, sh_bf, N);
    k_place<<<edge4Blocks, TPB, 0, stream>>>(rowI, colI, off, rank, csr_src, E);

    // iteration 1: scur = sh_bf -> writes only sA_bf (raw out1 never consumed)
    k_calcM<<<nodeWaveBlocks, TPB, 0, stream>>>(csr_src, off, deg, dis, sh_bf, Mcsr, alpha, N);
    k_gather<<<nodeWaveBlocks, TPB, 0, stream>>>(csr_src, off, deg, dis, alpha, Mcsr,
                                                 sh_bf, h, (float*)nullptr, sA_bf, N);

    // iteration 2: scur = sA_bf -> writes raw out2 (f32)
    k_calcM<<<nodeWaveBlocks, TPB, 0, stream>>>(csr_src, off, deg, dis, sA_bf, Mcsr, alpha, N);
    k_gather<<<nodeWaveBlocks, TPB, 0, stream>>>(csr_src, off, deg, dis, alpha, Mcsr,
                                                 sA_bf, h, out2, (u16*)nullptr, N);

    // output head via MFMA; 64 rows/block
    k_head<<<(N + 63) / 64, TPB, 0, stream>>>(out2, W2, b2, y, N, OUT);
}